// Round 4
// baseline (231.807 us; speedup 1.0000x reference)
//
#include <hip/hip_runtime.h>
#include <hip/hip_bf16.h>

#define TEMP_INV (1.0f / 0.07f)
#define LOG2E 1.4426950408889634f
#define LN2 0.6931471805599453f
#define NSPLIT 8
#define CFIX 21.0f

typedef __attribute__((ext_vector_type(4))) float f32x4;
typedef __attribute__((ext_vector_type(8))) int i32x8;

__device__ __forceinline__ void gload16(const unsigned char* g, unsigned char* l) {
  __builtin_amdgcn_global_load_lds(
      (const __attribute__((address_space(1))) void*)g,
      (__attribute__((address_space(3))) void*)l, 16, 0, 0);
}

// ---------------- Kernel 1: L2-normalize, write fp8(e4m3) feats x16, cross ---
__global__ __launch_bounds__(256) void norm_kernel(
    const float* __restrict__ A, const float* __restrict__ P,
    unsigned char* __restrict__ F, float* __restrict__ cross, int B, int D) {
  const int row = blockIdx.x;
  const int t = threadIdx.x;
  const float4* a4 = reinterpret_cast<const float4*>(A + (size_t)row * D);
  const float4* p4 = reinterpret_cast<const float4*>(P + (size_t)row * D);
  const int n4 = D >> 2;
  float sa = 0.f, sp = 0.f, sx = 0.f;
  for (int i = t; i < n4; i += 256) {
    float4 av = a4[i], pv = p4[i];
    sa += av.x * av.x + av.y * av.y + av.z * av.z + av.w * av.w;
    sp += pv.x * pv.x + pv.y * pv.y + pv.z * pv.z + pv.w * pv.w;
    sx += av.x * pv.x + av.y * pv.y + av.z * pv.z + av.w * pv.w;
  }
#pragma unroll
  for (int off = 32; off; off >>= 1) {
    sa += __shfl_down(sa, off);
    sp += __shfl_down(sp, off);
    sx += __shfl_down(sx, off);
  }
  __shared__ float red[3][4];
  const int wid = t >> 6, lane = t & 63;
  if (lane == 0) { red[0][wid] = sa; red[1][wid] = sp; red[2][wid] = sx; }
  __syncthreads();
  sa = red[0][0] + red[0][1] + red[0][2] + red[0][3];
  sp = red[1][0] + red[1][1] + red[1][2] + red[1][3];
  sx = red[2][0] + red[2][1] + red[2][2] + red[2][3];
  const float ia = rsqrtf(sa) * 16.f, ip = rsqrtf(sp) * 16.f;  // x16 for e4m3
  unsigned char* fa = F + (size_t)row * D;
  unsigned char* fp = F + (size_t)(B + row) * D;
  for (int i = t; i < n4; i += 256) {
    float4 av = a4[i], pv = p4[i];
    int qa = 0, qp = 0;
    qa = __builtin_amdgcn_cvt_pk_fp8_f32(av.x * ia, av.y * ia, qa, false);
    qa = __builtin_amdgcn_cvt_pk_fp8_f32(av.z * ia, av.w * ia, qa, true);
    qp = __builtin_amdgcn_cvt_pk_fp8_f32(pv.x * ip, pv.y * ip, qp, false);
    qp = __builtin_amdgcn_cvt_pk_fp8_f32(pv.z * ip, pv.w * ip, qp, true);
    reinterpret_cast<int*>(fa)[i] = qa;
    reinterpret_cast<int*>(fp)[i] = qp;
  }
  if (t == 0) cross[row] = sx * rsqrtf(sa) * rsqrtf(sp);
}

// ---------------- Kernel 2: fused Gram (MX-fp8) + fixed-max partial sums -----
// 256x256 tile, K-tile 128 (one MX k-step), 4 regions of 32KB (2buf x A/B).
// Region layout (256 rows x 128B): row = bank period; 16B chunk c' = c^(row&7)
// -> conflict-free per 8-lane group for both staging and b128 frag reads.
#define BMI 256
#define NJT 4            /* (NN/NSPLIT)/256 */
#define VT (NJT * 8)     /* K-128 tiles per block: 4 jt x (1024/128) */

__global__ __launch_bounds__(512, 2) void gram_lse_kernel(
    const unsigned char* __restrict__ F, float* __restrict__ part_l, int NN,
    int D) {
  __shared__ unsigned char lds[2][2][32768];  // [buf][A=0/B=1][32KB region]
  const int r0 = blockIdx.x * BMI;            // i rows (B operand, N side)
  const int c0 = blockIdx.y * (NN / NSPLIT);  // j chunk base (A operand, M)
  const int t = threadIdx.x;
  const int lane = t & 63, w = t >> 6;
  const int lo = lane & 15, hi = lane >> 4;
  const int wr = w >> 2, wn = w & 3;  // wr: j-half(128), wn: i-quarter(64)

  const unsigned char* FA = F + (size_t)c0 * 1024;
  const unsigned char* FB = F + (size_t)r0 * 1024;

  // staging: instr g of wave w covers LDS chunks (w*4+g)*64 + lane
  const int srow = lane >> 3;                 // 0..7
  const int sc = (lane & 7) ^ srow;           // swizzled chunk
  const int sg0 = ((w * 4 + 0) * 8 + srow) * 1024 + sc * 16;
  const int sg1 = ((w * 4 + 1) * 8 + srow) * 1024 + sc * 16;
  const int sg2 = ((w * 4 + 2) * 8 + srow) * 1024 + sc * 16;
  const int sg3 = ((w * 4 + 3) * 8 + srow) * 1024 + sc * 16;
  const int db0 = (w * 4 + 0) * 1024;
  const int db1 = (w * 4 + 1) * 1024;
  const int db2 = (w * 4 + 2) * 1024;
  const int db3 = (w * 4 + 3) * 1024;

  // fragment read bases (bytes in region); frag(mf) = [base + mf*2048] and ^16
  const int cl = ((2 * hi) ^ (lo & 7)) * 16;
  const int aBase = wr * 16384 + lo * 128 + cl;
  const int bBase = wn * 8192 + lo * 128 + cl;

#define STAGE_A(V, BUF)                                                  \
  do {                                                                   \
    int v_ = (V); if (v_ > VT - 1) v_ = VT - 1;                          \
    const int o_ = (v_ >> 3) * 262144 + (v_ & 7) * 128;                  \
    gload16(FA + o_ + sg0, &lds[BUF][0][db0]);                           \
    gload16(FA + o_ + sg1, &lds[BUF][0][db1]);                           \
    gload16(FA + o_ + sg2, &lds[BUF][0][db2]);                           \
    gload16(FA + o_ + sg3, &lds[BUF][0][db3]);                           \
  } while (0)
#define STAGE_B(V, BUF)                                                  \
  do {                                                                   \
    int v_ = (V); if (v_ > VT - 1) v_ = VT - 1;                          \
    const int o_ = (v_ & 7) * 128;                                       \
    gload16(FB + o_ + sg0, &lds[BUF][1][db0]);                           \
    gload16(FB + o_ + sg1, &lds[BUF][1][db1]);                           \
    gload16(FB + o_ + sg2, &lds[BUF][1][db2]);                           \
    gload16(FB + o_ + sg3, &lds[BUF][1][db3]);                           \
  } while (0)

  f32x4 acc[8][4];
  i32x8 bfr[4];
  float l_acc[4] = {0.f, 0.f, 0.f, 0.f};
  const float scl = LOG2E * TEMP_INV / 256.f;  // descale x16*x16 feats

#define PHASE(BUF, MH, RDB, STAGE_STMT, W4)                                    \
  do {                                                                         \
    const unsigned char* RA_ = &lds[BUF][0][0];                                \
    const unsigned char* RB_ = &lds[BUF][1][0];                                \
    if (RDB) {                                                                 \
      _Pragma("unroll") for (int nf = 0; nf < 4; ++nf) {                       \
        int4 q0 = *(const int4*)(RB_ + bBase + nf * 2048);                     \
        int4 q1 = *(const int4*)(RB_ + (bBase ^ 16) + nf * 2048);              \
        bfr[nf][0] = q0.x; bfr[nf][1] = q0.y; bfr[nf][2] = q0.z;               \
        bfr[nf][3] = q0.w; bfr[nf][4] = q1.x; bfr[nf][5] = q1.y;               \
        bfr[nf][6] = q1.z; bfr[nf][7] = q1.w;                                  \
      }                                                                        \
    }                                                                          \
    i32x8 af[4];                                                               \
    _Pragma("unroll") for (int m = 0; m < 4; ++m) {                            \
      int4 q0 = *(const int4*)(RA_ + aBase + ((MH)*4 + m) * 2048);             \
      int4 q1 = *(const int4*)(RA_ + (aBase ^ 16) + ((MH)*4 + m) * 2048);      \
      af[m][0] = q0.x; af[m][1] = q0.y; af[m][2] = q0.z; af[m][3] = q0.w;      \
      af[m][4] = q1.x; af[m][5] = q1.y; af[m][6] = q1.z; af[m][7] = q1.w;      \
    }                                                                          \
    STAGE_STMT;                                                                \
    if (W4) asm volatile("s_waitcnt vmcnt(4)" ::: "memory");                   \
    asm volatile("" ::: "memory");                                             \
    __builtin_amdgcn_s_barrier();                                              \
    asm volatile("" ::: "memory");                                             \
    __builtin_amdgcn_s_setprio(1);                                             \
    _Pragma("unroll") for (int m = 0; m < 4; ++m)                              \
      _Pragma("unroll") for (int nf = 0; nf < 4; ++nf)                         \
        acc[(MH)*4 + m][nf] = __builtin_amdgcn_mfma_scale_f32_16x16x128_f8f6f4(\
            af[m], bfr[nf], acc[(MH)*4 + m][nf], 0, 0, 0, 127, 0, 127);        \
    __builtin_amdgcn_s_setprio(0);                                             \
    asm volatile("" ::: "memory");                                             \
    __builtin_amdgcn_s_barrier();                                              \
    asm volatile("" ::: "memory");                                             \
  } while (0)

  // prologue: emulate prev-iter stages {B[0]->buf0, A[0]->buf0, B[1]->buf1}
  STAGE_B(0, 0);
  STAGE_A(0, 0);
  STAGE_B(1, 1);
  asm volatile("s_waitcnt vmcnt(4)" ::: "memory");
  __builtin_amdgcn_s_barrier();
  asm volatile("" ::: "memory");

  for (int jt = 0; jt < NJT; ++jt) {
#pragma unroll
    for (int a = 0; a < 8; ++a)
#pragma unroll
      for (int b = 0; b < 4; ++b) acc[a][b] = (f32x4){0.f, 0.f, 0.f, 0.f};

    for (int u = 0; u < 4; ++u) {
      const int v0 = jt * 8 + u * 2;  // even K-128 tile -> buf0; odd -> buf1
      PHASE(0, 0, 1, STAGE_A(v0 + 1, 1), 0);  // P1
      PHASE(0, 1, 0, STAGE_B(v0 + 2, 0), 1);  // P2 vmcnt(4)
      PHASE(1, 0, 1, STAGE_A(v0 + 2, 0), 0);  // P3
      PHASE(1, 1, 0, STAGE_B(v0 + 3, 1), 1);  // P4 vmcnt(4)
    }

    // epilogue: fixed-max exp accumulate
    // acc[mf][nf][rg]: j = c0 + jt*256 + wr*128 + mf*16 + hi*4 + rg
    //                  i = r0 + wn*64 + nf*16 + lo
    {
      const int jb2 = c0 + jt * 256 + wr * 128;
#pragma unroll
      for (int nf = 0; nf < 4; ++nf) {
        const int dg = (r0 + wn * 64 + nf * 16 + lo) - jb2;
        float s = 0.f;
#pragma unroll
        for (int mf = 0; mf < 8; ++mf)
#pragma unroll
          for (int rg = 0; rg < 4; ++rg) {
            const int jloc = mf * 16 + hi * 4 + rg;
            const float e = exp2f(acc[mf][nf][rg] * scl - CFIX);
            s += (dg == jloc) ? 0.f : e;
          }
        l_acc[nf] += s;
      }
    }
  }

  asm volatile("s_waitcnt vmcnt(0)" ::: "memory");

#pragma unroll
  for (int nf = 0; nf < 4; ++nf) {
    float v = l_acc[nf];
    v += __shfl_xor(v, 16);
    v += __shfl_xor(v, 32);
    if (hi == 0) {
      const int ig = r0 + wn * 64 + nf * 16 + lo;
      part_l[(size_t)(blockIdx.y * 2 + wr) * NN + ig] = v;
    }
  }
#undef PHASE
#undef STAGE_A
#undef STAGE_B
}

// ---------------- Kernel 3a: per-row combine -> per-block partial sums -------
__global__ __launch_bounds__(256) void finalize_part(
    const float* __restrict__ part_l, const float* __restrict__ cross,
    const int* __restrict__ labels, float* __restrict__ bsum,
    float* __restrict__ bcnt, int B, int nparts) {
  const int NN = 2 * B;
  const int i = blockIdx.x * 256 + threadIdx.x;
  float sum = 0.f, cnt = 0.f;
  if (i < NN) {
    float L = 0.f;
    for (int p = 0; p < nparts; ++p) L += part_l[(size_t)p * NN + i];
    const float lse = LN2 * (CFIX + log2f(L));
    const float lab = (float)labels[i % B];
    sum = (lse - cross[i % B] * TEMP_INV) * lab;
    cnt = lab;
  }
#pragma unroll
  for (int off = 32; off; off >>= 1) {
    sum += __shfl_down(sum, off);
    cnt += __shfl_down(cnt, off);
  }
  __shared__ float rs[4], rc[4];
  const int wid = threadIdx.x >> 6, lane = threadIdx.x & 63;
  if (lane == 0) { rs[wid] = sum; rc[wid] = cnt; }
  __syncthreads();
  if (threadIdx.x == 0) {
    bsum[blockIdx.x] = rs[0] + rs[1] + rs[2] + rs[3];
    bcnt[blockIdx.x] = rc[0] + rc[1] + rc[2] + rc[3];
  }
}

// ---------------- Kernel 3b: final reduce ------------------------------------
__global__ __launch_bounds__(64) void finalize_final(
    const float* __restrict__ bsum, const float* __restrict__ bcnt,
    float* __restrict__ out, int nb) {
  const int t = threadIdx.x;
  float s = (t < nb) ? bsum[t] : 0.f;
  float c = (t < nb) ? bcnt[t] : 0.f;
#pragma unroll
  for (int off = 32; off; off >>= 1) {
    s += __shfl_down(s, off);
    c += __shfl_down(c, off);
  }
  if (t == 0) out[0] = (c > 0.f) ? s / c : 0.f;
}

extern "C" void kernel_launch(void* const* d_in, const int* in_sizes, int n_in,
                              void* d_out, int out_size, void* d_ws, size_t ws_size,
                              hipStream_t stream) {
  const float* A = (const float*)d_in[0];
  const float* P = (const float*)d_in[1];
  const int* labels = (const int*)d_in[2];
  float* out = (float*)d_out;
  const int B = in_sizes[2];
  const int D = in_sizes[0] / B;
  const int NN = 2 * B;

  char* ws = (char*)d_ws;
  unsigned char* F = (unsigned char*)ws;
  size_t off = (size_t)NN * D;  // fp8: 1 byte/elem
  off = (off + 255) & ~(size_t)255;
  float* cross = (float*)(ws + off);
  off += (size_t)B * sizeof(float);
  off = (off + 255) & ~(size_t)255;
  float* part_l = (float*)(ws + off);
  off += (size_t)2 * NSPLIT * NN * sizeof(float);
  off = (off + 255) & ~(size_t)255;
  float* bsum = (float*)(ws + off);
  off += 64 * sizeof(float);
  float* bcnt = (float*)(ws + off);

  norm_kernel<<<B, 256, 0, stream>>>(A, P, F, cross, B, D);
  dim3 g2(NN / BMI, NSPLIT);
  gram_lse_kernel<<<g2, 512, 0, stream>>>(F, part_l, NN, D);
  const int nb = (NN + 255) / 256;  // 32
  finalize_part<<<nb, 256, 0, stream>>>(part_l, cross, labels, bsum, bcnt, B,
                                        2 * NSPLIT);
  finalize_final<<<1, 64, 0, stream>>>(bsum, bcnt, out, nb);
}

// Round 6
// 143.700 us; speedup vs baseline: 1.6131x; 1.6131x over previous
//
#include <hip/hip_runtime.h>
#include <hip/hip_bf16.h>

#define TEMP_INV (1.0f / 0.07f)
#define LOG2E 1.4426950408889634f
#define LN2 0.6931471805599453f
#define CFIX 21.0f

typedef __attribute__((ext_vector_type(4))) float f32x4;
typedef __attribute__((ext_vector_type(8))) short bf16x8;

__device__ __forceinline__ ushort f2bf(float x) {
  union { float f; unsigned u; } v; v.f = x;
  unsigned r = (v.u + 0x7fffu + ((v.u >> 16) & 1u)) >> 16;
  return (ushort)r;
}

__device__ __forceinline__ void gload16(const ushort* g, ushort* l) {
  __builtin_amdgcn_global_load_lds(
      (const __attribute__((address_space(1))) void*)g,
      (__attribute__((address_space(3))) void*)l, 16, 0, 0);
}

// ---------------- Kernel 0: zero the row-sum accumulator ---------------------
__global__ __launch_bounds__(256) void zero_kernel(float* __restrict__ p, int n) {
  const int i = blockIdx.x * 256 + threadIdx.x;
  if (i < n) p[i] = 0.f;
}

// ---------------- Kernel 1: L2-normalize rows, write bf16 feats, cross dot ----
__global__ __launch_bounds__(256) void norm_kernel(
    const float* __restrict__ A, const float* __restrict__ P,
    ushort* __restrict__ F, float* __restrict__ cross, int B, int D) {
  const int row = blockIdx.x;
  const int t = threadIdx.x;
  const float4* a4 = reinterpret_cast<const float4*>(A + (size_t)row * D);
  const float4* p4 = reinterpret_cast<const float4*>(P + (size_t)row * D);
  const int n4 = D >> 2;
  float sa = 0.f, sp = 0.f, sx = 0.f;
  for (int i = t; i < n4; i += 256) {
    float4 av = a4[i], pv = p4[i];
    sa += av.x * av.x + av.y * av.y + av.z * av.z + av.w * av.w;
    sp += pv.x * pv.x + pv.y * pv.y + pv.z * pv.z + pv.w * pv.w;
    sx += av.x * pv.x + av.y * pv.y + av.z * pv.z + av.w * pv.w;
  }
#pragma unroll
  for (int off = 32; off; off >>= 1) {
    sa += __shfl_down(sa, off);
    sp += __shfl_down(sp, off);
    sx += __shfl_down(sx, off);
  }
  __shared__ float red[3][4];
  const int wid = t >> 6, lane = t & 63;
  if (lane == 0) { red[0][wid] = sa; red[1][wid] = sp; red[2][wid] = sx; }
  __syncthreads();
  sa = red[0][0] + red[0][1] + red[0][2] + red[0][3];
  sp = red[1][0] + red[1][1] + red[1][2] + red[1][3];
  sx = red[2][0] + red[2][1] + red[2][2] + red[2][3];
  const float ia = rsqrtf(sa), ip = rsqrtf(sp);
  ushort* fa = F + (size_t)row * D;
  ushort* fp = F + (size_t)(B + row) * D;
  for (int i = t; i < n4; i += 256) {
    float4 av = a4[i], pv = p4[i];
    ushort4 oa, op;
    oa.x = f2bf(av.x * ia); oa.y = f2bf(av.y * ia);
    oa.z = f2bf(av.z * ia); oa.w = f2bf(av.w * ia);
    op.x = f2bf(pv.x * ip); op.y = f2bf(pv.y * ip);
    op.z = f2bf(pv.z * ip); op.w = f2bf(pv.w * ip);
    reinterpret_cast<ushort4*>(fa)[i] = oa;
    reinterpret_cast<ushort4*>(fp)[i] = op;
  }
  if (t == 0) cross[row] = sx * ia * ip;
}

// ---------------- Kernel 2: triangular fused Gram + dual-side exp sums -------
// One 256x256 triangle tile (bx<=by), FULL K=1024 per block (no K-split: exp
// does not commute with K-partial sums — R5 failure). R3's verified 8-phase
// BK=64 dbuf schedule, unchanged. Dual-side epilogue feeds i-rows (bx panel)
// and j-rows (by panel) via atomicAdd into lsum; diagonal tiles mask self
// pairs and skip the j-side.
// LDS region layout (256x32 bf16, 16KB): paired rows, XOR-swizzled 16B chunks
// (verified conflict-free R2/R3): elem (trow,k): lrow=trow>>1;
// cu=(trow&1)*4+(k>>3); c=cu^(lrow&7); byte=lrow*128+c*16+(k&7)*2.
#define VT 16  /* K-64 tiles per block: D/64 */

__global__ __launch_bounds__(512, 2) void gram_lse_kernel(
    const ushort* __restrict__ F, float* __restrict__ lsum, int NN, int D) {
  __shared__ ushort lds[2][2][2][8192];  // [buf][A=0/B=1][khalf][16KB region]
  const int lin = blockIdx.x;  // triangle index
  int by = (int)((sqrtf(8.f * (float)lin + 1.f) - 1.f) * 0.5f);
  while ((by + 1) * (by + 2) / 2 <= lin) ++by;
  while (by * (by + 1) / 2 > lin) --by;
  const int bx = lin - by * (by + 1) / 2;  // bx <= by
  const int r0 = bx * 256;  // i rows (B operand, N side)
  const int c0 = by * 256;  // j rows (A operand, M side)
  const bool offdiag = (bx != by);

  const int t = threadIdx.x;
  const int lane = t & 63, w = t >> 6;
  const int lo = lane & 15, hi = lane >> 4;
  const int wr = w >> 2, wn = w & 3;  // wr: j-half(128), wn: i-quarter(64)

  // staging map (per thread): segments w and w+8 of each region
  const int l3 = lane >> 3, l7 = lane & 7;
  const int cu = l7 ^ l3;
  const int sub = cu >> 2, kc = cu & 3;
  const int trow0 = w * 16 + l3 * 2 + sub;
  const int trow1 = (w + 8) * 16 + l3 * 2 + sub;
  const ushort* baseA0 = F + (size_t)(c0 + trow0) * D + kc * 8;
  const ushort* baseA1 = F + (size_t)(c0 + trow1) * D + kc * 8;
  const ushort* baseB0 = F + (size_t)(r0 + trow0) * D + kc * 8;
  const ushort* baseB1 = F + (size_t)(r0 + trow1) * D + kc * 8;
  const int dst0 = w * 512, dst1 = (w + 8) * 512;  // ushort offsets (uniform)

  // fragment read base (bytes within a region)
  const int cA = (((lo & 1) << 2) | hi) ^ (lo >> 1);
  const int rdBase = (lo >> 1) * 128 + cA * 16;

#define STAGE_A(T, KS, BUF)                                              \
  do {                                                                   \
    int c_ = (T); if (c_ > VT - 1) c_ = VT - 1;                          \
    const size_t o_ = (size_t)(c_ * 64 + (KS) * 32);                     \
    gload16(baseA0 + o_, &lds[BUF][0][KS][dst0]);                        \
    gload16(baseA1 + o_, &lds[BUF][0][KS][dst1]);                        \
  } while (0)
#define STAGE_B(T, KS, BUF)                                              \
  do {                                                                   \
    int c_ = (T); if (c_ > VT - 1) c_ = VT - 1;                          \
    const size_t o_ = (size_t)(c_ * 64 + (KS) * 32);                     \
    gload16(baseB0 + o_, &lds[BUF][1][KS][dst0]);                        \
    gload16(baseB1 + o_, &lds[BUF][1][KS][dst1]);                        \
  } while (0)

  f32x4 acc[8][4];
  bf16x8 bfr[4];
  const float scl = LOG2E * TEMP_INV;

#define PHASE(BUF, MH, KS, READB, STAGE_STMT, WAIT4)                          \
  do {                                                                        \
    const char* RA_ = (const char*)&lds[BUF][0][KS][0];                       \
    const char* RB_ = (const char*)&lds[BUF][1][KS][0];                       \
    if (READB) {                                                              \
      _Pragma("unroll") for (int nf = 0; nf < 4; ++nf)                        \
          bfr[nf] = *(const bf16x8*)(RB_ + wn * 4096 + nf * 1024 + rdBase);   \
    }                                                                         \
    bf16x8 af[4];                                                             \
    _Pragma("unroll") for (int m = 0; m < 4; ++m)                             \
        af[m] = *(const bf16x8*)(RA_ + wr * 8192 + ((MH)*4 + m) * 1024 +      \
                                 rdBase);                                     \
    STAGE_STMT;                                                               \
    if (WAIT4) asm volatile("s_waitcnt vmcnt(4)" ::: "memory");               \
    asm volatile("" ::: "memory");                                            \
    __builtin_amdgcn_s_barrier();                                             \
    asm volatile("" ::: "memory");                                            \
    __builtin_amdgcn_s_setprio(1);                                            \
    _Pragma("unroll") for (int m = 0; m < 4; ++m)                             \
      _Pragma("unroll") for (int nf = 0; nf < 4; ++nf)                        \
          acc[(MH)*4 + m][nf] = __builtin_amdgcn_mfma_f32_16x16x32_bf16(      \
              af[m], bfr[nf], acc[(MH)*4 + m][nf], 0, 0, 0);                  \
    __builtin_amdgcn_s_setprio(0);                                            \
    asm volatile("" ::: "memory");                                            \
    __builtin_amdgcn_s_barrier();                                             \
    asm volatile("" ::: "memory");                                            \
  } while (0)

#pragma unroll
  for (int a = 0; a < 8; ++a)
#pragma unroll
    for (int b = 0; b < 4; ++b) acc[a][b] = (f32x4){0.f, 0.f, 0.f, 0.f};

  // prologue: 7 half-tiles (A1k1 is staged by iter0's P1)
  STAGE_A(0, 0, 0); STAGE_B(0, 0, 0);
  STAGE_A(0, 1, 0); STAGE_B(0, 1, 0);
  STAGE_A(1, 0, 1); STAGE_B(1, 0, 1);
  STAGE_B(1, 1, 1);
  asm volatile("s_waitcnt vmcnt(6)" ::: "memory");
  __builtin_amdgcn_s_barrier();
  asm volatile("" ::: "memory");

  for (int it = 0; it < 8; ++it) {
    const int tt = it * 2;  // even tile -> buf0; odd -> buf1
    PHASE(0, 0, 0, true,  STAGE_A(tt + 1, 1, 1), false);  // P1
    PHASE(0, 1, 0, false, STAGE_B(tt + 2, 0, 0), false);  // P2
    PHASE(0, 0, 1, true,  STAGE_A(tt + 2, 0, 0), false);  // P3
    PHASE(0, 1, 1, false, STAGE_B(tt + 2, 1, 0), true);   // P4 vmcnt(4)
    PHASE(1, 0, 0, true,  STAGE_A(tt + 2, 1, 0), false);  // P5
    PHASE(1, 1, 0, false, STAGE_B(tt + 3, 0, 1), false);  // P6
    PHASE(1, 0, 1, true,  STAGE_A(tt + 3, 0, 1), false);  // P7
    PHASE(1, 1, 1, false, STAGE_B(tt + 3, 1, 1), true);   // P8 vmcnt(4)
  }

  // ---- dual-side epilogue (full-K dots -> exp is now correct) ----
  // acc[mf][nf][rg]: j = c0 + wr*128 + mf*16 + hi*4 + rg
  //                  i = r0 + wn*64 + nf*16 + lo
  float s_i[4] = {0.f, 0.f, 0.f, 0.f};
  float s_j[32];
#pragma unroll
  for (int q = 0; q < 32; ++q) s_j[q] = 0.f;
  {
    const int jb2 = c0 + wr * 128;
#pragma unroll
    for (int nf = 0; nf < 4; ++nf) {
      const int dg = (r0 + wn * 64 + nf * 16 + lo) - jb2;
#pragma unroll
      for (int mf = 0; mf < 8; ++mf)
#pragma unroll
        for (int rg = 0; rg < 4; ++rg) {
          const int jloc = mf * 16 + hi * 4 + rg;
          const float e =
              (dg == jloc) ? 0.f : exp2f(acc[mf][nf][rg] * scl - CFIX);
          s_i[nf] += e;
          s_j[mf * 4 + rg] += e;
        }
    }
  }
  // i-side: reduce over hi groups (this wave's j coverage), add to rows i
#pragma unroll
  for (int nf = 0; nf < 4; ++nf) {
    float v = s_i[nf];
    v += __shfl_xor(v, 16);
    v += __shfl_xor(v, 32);
    if (hi == 0) atomicAdd(&lsum[r0 + wn * 64 + nf * 16 + lo], v);
  }
  // j-side: reduce over lo lanes (this wave's i coverage), add to rows j
  if (offdiag) {
#pragma unroll
    for (int q = 0; q < 32; ++q) {
      float v = s_j[q];
      v += __shfl_xor(v, 1);
      v += __shfl_xor(v, 2);
      v += __shfl_xor(v, 4);
      v += __shfl_xor(v, 8);
      if (lo == 0)
        atomicAdd(&lsum[c0 + wr * 128 + (q >> 2) * 16 + hi * 4 + (q & 3)], v);
    }
  }

  asm volatile("s_waitcnt vmcnt(0)" ::: "memory");
#undef PHASE
#undef STAGE_A
#undef STAGE_B
}

// ---------------- Kernel 3a: per-row loss -> per-block partial sums ----------
__global__ __launch_bounds__(256) void finalize_part(
    const float* __restrict__ lsum, const float* __restrict__ cross,
    const int* __restrict__ labels, float* __restrict__ bsum,
    float* __restrict__ bcnt, int B) {
  const int NN = 2 * B;
  const int i = blockIdx.x * 256 + threadIdx.x;
  float sum = 0.f, cnt = 0.f;
  if (i < NN) {
    const float lse = LN2 * (CFIX + log2f(lsum[i]));
    const float lab = (float)labels[i % B];
    sum = (lse - cross[i % B] * TEMP_INV) * lab;
    cnt = lab;
  }
#pragma unroll
  for (int off = 32; off; off >>= 1) {
    sum += __shfl_down(sum, off);
    cnt += __shfl_down(cnt, off);
  }
  __shared__ float rs[4], rc[4];
  const int wid = threadIdx.x >> 6, lane = threadIdx.x & 63;
  if (lane == 0) { rs[wid] = sum; rc[wid] = cnt; }
  __syncthreads();
  if (threadIdx.x == 0) {
    bsum[blockIdx.x] = rs[0] + rs[1] + rs[2] + rs[3];
    bcnt[blockIdx.x] = rc[0] + rc[1] + rc[2] + rc[3];
  }
}

// ---------------- Kernel 3b: final reduce ------------------------------------
__global__ __launch_bounds__(64) void finalize_final(
    const float* __restrict__ bsum, const float* __restrict__ bcnt,
    float* __restrict__ out, int nb) {
  const int t = threadIdx.x;
  float s = (t < nb) ? bsum[t] : 0.f;
  float c = (t < nb) ? bcnt[t] : 0.f;
#pragma unroll
  for (int off = 32; off; off >>= 1) {
    s += __shfl_down(s, off);
    c += __shfl_down(c, off);
  }
  if (t == 0) out[0] = (c > 0.f) ? s / c : 0.f;
}

extern "C" void kernel_launch(void* const* d_in, const int* in_sizes, int n_in,
                              void* d_out, int out_size, void* d_ws, size_t ws_size,
                              hipStream_t stream) {
  const float* A = (const float*)d_in[0];
  const float* P = (const float*)d_in[1];
  const int* labels = (const int*)d_in[2];
  float* out = (float*)d_out;
  const int B = in_sizes[2];
  const int D = in_sizes[0] / B;
  const int NN = 2 * B;

  char* ws = (char*)d_ws;
  ushort* F = (ushort*)ws;
  size_t off = (size_t)NN * D * sizeof(ushort);
  off = (off + 255) & ~(size_t)255;
  float* cross = (float*)(ws + off);
  off += (size_t)B * sizeof(float);
  off = (off + 255) & ~(size_t)255;
  float* lsum = (float*)(ws + off);
  off += (size_t)NN * sizeof(float);
  off = (off + 255) & ~(size_t)255;
  float* bsum = (float*)(ws + off);
  off += 64 * sizeof(float);
  float* bcnt = (float*)(ws + off);

  zero_kernel<<<(NN + 255) / 256, 256, 0, stream>>>(lsum, NN);
  norm_kernel<<<B, 256, 0, stream>>>(A, P, F, cross, B, D);
  const int nrb = NN / 256;              // 32 row-panels
  const int ntri = nrb * (nrb + 1) / 2;  // 528 triangle tiles, full K each
  gram_lse_kernel<<<ntri, 512, 0, stream>>>(F, lsum, NN, D);
  const int nb = (NN + 255) / 256;  // 32
  finalize_part<<<nb, 256, 0, stream>>>(lsum, cross, labels, bsum, bcnt, B);
  finalize_final<<<1, 64, 0, stream>>>(bsum, bcnt, out, nb);
}